// Round 1
// baseline (70.977 us; speedup 1.0000x reference)
//
#include <hip/hip_runtime.h>
#include <hip/hip_bf16.h>

using bf16x8 = __bf16 __attribute__((ext_vector_type(8)));
using f32x4  = float __attribute__((ext_vector_type(4)));

constexpr int HWT   = 784;
constexpr int CIN   = 64;
constexpr int DOUT  = 128;
constexpr int BATCH = 512;
constexpr int NROWS = BATCH * HWT;               // 401408
constexpr int ROWS_PER_BLOCK = 128;
constexpr int NBLOCKS = NROWS / ROWS_PER_BLOCK;  // 3136

// out[n, d] = sum_c x[partner(n), c] * W[d, c]; partner = XOR within batch pair.
// attn output = all ones (size-1 softmax).
__global__ __launch_bounds__(256)
void qkv_xor_gemm(const float* __restrict__ x,
                  const float* __restrict__ W,
                  float* __restrict__ out)
{
  __shared__ __bf16 w_lds[DOUT][72];   // stride 72 bf16 = 144 B (not pow2 -> few conflicts)

  const int tid  = threadIdx.x;
  const int lane = tid & 63;
  const int wave = tid >> 6;
  const int dcol = lane & 15;          // MFMA n / m index
  const int krow = (lane >> 4) * 8;    // MFMA k base per lane group

  // ---- stage W (fp32 [128][64]) -> bf16 LDS
  {
    const f32x4* W4 = reinterpret_cast<const f32x4*>(W);
    for (int i = tid; i < DOUT * CIN / 4; i += 256) {
      f32x4 wv = W4[i];
      int d = i >> 4;           // 16 float4 per 64-wide row
      int c = (i & 15) * 4;
      w_lds[d][c + 0] = (__bf16)wv[0];
      w_lds[d][c + 1] = (__bf16)wv[1];
      w_lds[d][c + 2] = (__bf16)wv[2];
      w_lds[d][c + 3] = (__bf16)wv[3];
    }
  }
  __syncthreads();

  // ---- B fragments to registers: B[k][n], n = dcol, k = krow + i, per k-tile
  bf16x8 bfrag[8][2];
#pragma unroll
  for (int dt = 0; dt < 8; ++dt) {
#pragma unroll
    for (int kt = 0; kt < 2; ++kt) {
      bfrag[dt][kt] =
          *reinterpret_cast<const bf16x8*>(&w_lds[dt * 16 + dcol][kt * 32 + krow]);
    }
  }

#pragma unroll
  for (int rt = 0; rt < 2; ++rt) {
    const int rbase = blockIdx.x * ROWS_PER_BLOCK + rt * 64 + wave * 16;

    // A fragment: row = rbase + dcol (XOR-partner source), k = krow..krow+7 per tile
    const int r   = rbase + dcol;
    const int b   = r / HWT;
    const int t   = r - b * HWT;
    const int src = (b ^ 1) * HWT + t;
    const float* xp = x + (size_t)src * CIN + krow;
    f32x4 x0 = *reinterpret_cast<const f32x4*>(xp);
    f32x4 x1 = *reinterpret_cast<const f32x4*>(xp + 4);
    f32x4 x2 = *reinterpret_cast<const f32x4*>(xp + 32);
    f32x4 x3 = *reinterpret_cast<const f32x4*>(xp + 36);

    bf16x8 a0, a1;
#pragma unroll
    for (int i = 0; i < 4; ++i) {
      a0[i]     = (__bf16)x0[i];
      a0[i + 4] = (__bf16)x1[i];
      a1[i]     = (__bf16)x2[i];
      a1[i + 4] = (__bf16)x3[i];
    }

    f32x4 acc[8];
#pragma unroll
    for (int dt = 0; dt < 8; ++dt) acc[dt] = (f32x4){0.f, 0.f, 0.f, 0.f};
#pragma unroll
    for (int dt = 0; dt < 8; ++dt) {
      acc[dt] = __builtin_amdgcn_mfma_f32_16x16x32_bf16(a0, bfrag[dt][0], acc[dt], 0, 0, 0);
      acc[dt] = __builtin_amdgcn_mfma_f32_16x16x32_bf16(a1, bfrag[dt][1], acc[dt], 0, 0, 0);
    }

    // store: row = rbase + (lane>>4)*4 + i, col = dt*16 + dcol  (m89-verified C/D map)
    const int rs = rbase + (lane >> 4) * 4;
#pragma unroll
    for (int dt = 0; dt < 8; ++dt) {
#pragma unroll
      for (int i = 0; i < 4; ++i) {
        out[(size_t)(rs + i) * DOUT + dt * 16 + dcol] = acc[dt][i];
      }
    }
  }

  // attn output: ones [NROWS] appended after cross_x
  if (tid < ROWS_PER_BLOCK) {
    out[(size_t)NROWS * DOUT + (size_t)blockIdx.x * ROWS_PER_BLOCK + tid] = 1.0f;
  }
}

extern "C" void kernel_launch(void* const* d_in, const int* in_sizes, int n_in,
                              void* d_out, int out_size, void* d_ws, size_t ws_size,
                              hipStream_t stream)
{
  const float* x = (const float*)d_in[0];
  const float* W = (const float*)d_in[1];
  float* out = (float*)d_out;
  qkv_xor_gemm<<<NBLOCKS, 256, 0, stream>>>(x, W, out);
}